// Round 2
// baseline (1238.430 us; speedup 1.0000x reference)
//
#include <hip/hip_runtime.h>
#include <cstdint>

#define B_ 2
#define E_ 16
#define H_ 160
#define W_ 288
#define N_ 12
#define T_ 2
#define HW_ (H_*W_)        // 46080
#define P_ (T_*HW_)        // 92160
#define NINST (B_*N_)      // 24
#define NBINS 32768        // err in [0,2) -> bin = min(32767, err*16384)

typedef unsigned long long u64;
typedef unsigned int u32;

__device__ inline float waveReduceSum(float v){
  #pragma unroll
  for(int o=32;o>0;o>>=1) v += __shfl_down(v, o, 64);
  return v;
}

// ---------------- Pass A: masked sums (mean numerator) + count ----------------
__global__ void k_sums(const float* __restrict__ mf1, const float* __restrict__ mf2,
                       const int* __restrict__ gt,
                       float* __restrict__ sumEmb, float* __restrict__ cnt){
  int bn = blockIdx.x;               // 0..23
  int b  = bn / N_;
  int base = blockIdx.y * 1024;      // 90 chunks of 1024 px
  int t = base / HW_;
  int rbase = base - t*HW_;
  const float* ep = (t ? mf2 : mf1) + (size_t)b*E_*HW_;
  const int*   gp = gt + ((size_t)bn*T_ + t)*HW_;

  float acc[E_]; float c = 0.f;
  #pragma unroll
  for(int e=0;e<E_;e++) acc[e]=0.f;
  #pragma unroll
  for(int k=0;k<4;k++){
    int r = rbase + k*256 + threadIdx.x;
    float m = (float)gp[r];
    c += m;
    #pragma unroll
    for(int e=0;e<E_;e++) acc[e] = fmaf(m, ep[(size_t)e*HW_ + r], acc[e]);
  }
  __shared__ float red[E_+1];
  if(threadIdx.x < E_+1) red[threadIdx.x] = 0.f;
  __syncthreads();
  int lane = threadIdx.x & 63;
  #pragma unroll
  for(int e=0;e<E_;e++){
    float r = waveReduceSum(acc[e]);
    if(lane==0) atomicAdd(&red[e], r);
  }
  { float r = waveReduceSum(c); if(lane==0) atomicAdd(&red[E_], r); }
  __syncthreads();
  if(threadIdx.x < E_) atomicAdd(&sumEmb[bn*E_ + threadIdx.x], red[threadIdx.x]);
  if(threadIdx.x == E_) atomicAdd(&cnt[bn], red[E_]);
}

__global__ void k_fin_mean(const float* __restrict__ sumEmb, const float* __restrict__ cnt,
                           float* __restrict__ mean){
  int i = threadIdx.x;  // 384
  mean[i] = sumEmb[i] / cnt[i>>4];
}

// ---------------- Pass B: masked sum of (emb-mean)^2 -> variance ----------------
__global__ void k_var(const float* __restrict__ mf1, const float* __restrict__ mf2,
                      const int* __restrict__ gt, const float* __restrict__ mean,
                      float* __restrict__ sumD2){
  int bn = blockIdx.x;
  int b  = bn / N_;
  int base = blockIdx.y * 1024;
  int t = base / HW_;
  int rbase = base - t*HW_;
  const float* ep = (t ? mf2 : mf1) + (size_t)b*E_*HW_;
  const int*   gp = gt + ((size_t)bn*T_ + t)*HW_;

  float mn[E_];
  #pragma unroll
  for(int e=0;e<E_;e++) mn[e] = mean[bn*E_ + e];

  float acc[E_];
  #pragma unroll
  for(int e=0;e<E_;e++) acc[e]=0.f;
  #pragma unroll
  for(int k=0;k<4;k++){
    int r = rbase + k*256 + threadIdx.x;
    float m = (float)gp[r];
    #pragma unroll
    for(int e=0;e<E_;e++){
      float d = ep[(size_t)e*HW_ + r] - mn[e];
      acc[e] = fmaf(m*d, d, acc[e]);
    }
  }
  __shared__ float red[E_];
  if(threadIdx.x < E_) red[threadIdx.x] = 0.f;
  __syncthreads();
  int lane = threadIdx.x & 63;
  #pragma unroll
  for(int e=0;e<E_;e++){
    float r = waveReduceSum(acc[e]);
    if(lane==0) atomicAdd(&red[e], r);
  }
  __syncthreads();
  if(threadIdx.x < E_) atomicAdd(&sumD2[bn*E_ + threadIdx.x], red[threadIdx.x]);
}

__global__ void k_fin_var(const float* __restrict__ sumD2, const float* __restrict__ cnt,
                          float* __restrict__ var){
  int i = threadIdx.x;  // 384
  var[i] = sumD2[i] / (cnt[i>>4] - 1.0f);
}

// ---------------- Pass C: errors + histogram of (count, labelsum) per bin ----
// err = 1 - logits*sign >= 0, binned linearly: bin = min(32767, err*16384).
// Wave-level leader loop aggregates all same-bin lanes into ONE u64 atomic
// (count<<32 | labelsum) -- errors cluster near 0 and 2, so same-address
// contention would otherwise serialize.
__global__ void k_err(const float* __restrict__ mf1, const float* __restrict__ mf2,
                      const int* __restrict__ gt, const float* __restrict__ mean,
                      const float* __restrict__ var,
                      float* __restrict__ err, u64* __restrict__ hist){
  __shared__ float sm[N_*E_], sv[N_*E_];
  int b = blockIdx.x;
  for(int i=threadIdx.x; i<N_*E_; i+=256){
    sm[i] = mean[b*N_*E_ + i];
    sv[i] = var [b*N_*E_ + i];
  }
  __syncthreads();
  int p = blockIdx.y*256 + threadIdx.x;   // 0..P_-1 exactly (360*256 = 92160)
  int t = p / HW_;
  int r = p - t*HW_;
  int lane = threadIdx.x & 63;
  const float* ep = (t ? mf2 : mf1) + (size_t)b*E_*HW_;
  float v[E_];
  #pragma unroll
  for(int e=0;e<E_;e++) v[e] = ep[(size_t)e*HW_ + r];

  #pragma unroll
  for(int n=0;n<N_;n++){
    int bn = b*N_ + n;
    float d = 0.f;
    #pragma unroll
    for(int e=0;e<E_;e++){
      float df = v[e] - sm[n*E_+e];
      d = fmaf(df*df, sv[n*E_+e], d);
    }
    float logits = 2.f*__expf(-0.5f*d) - 1.f;
    int   mi = gt[(size_t)bn*P_ + p];      // 0/1
    float sign = 2.f*(float)mi - 1.f;
    float ev = 1.f - logits*sign;          // >= 0
    err[(size_t)bn*P_ + p] = ev;
    u32 bin = (u32)min(NBINS-1, (int)(ev * (NBINS/2)));

    u64* hp = hist + (size_t)bn*NBINS;
    u64 mball = __ballot(mi != 0);
    u64 active = __ballot(1);
    while(active){
      int leader = __ffsll(active) - 1;
      u32 lbin = (u32)__shfl((int)bin, leader, 64);
      u64 match = __ballot(bin == lbin) & active;
      if(lane == leader){
        u64 cntm = (u64)__popcll(match);
        u64 labm = (u64)__popcll(match & mball);
        atomicAdd(&hp[lbin], (cntm<<32) | labm);
      }
      active &= ~match;
    }
  }
}

// ---------------- Pass D: per-instance descending exclusive scan over bins ---
// rc[bn][bin] = sum over bins' > bin of hist[bn][bin']  (packed count<<32|label)
__global__ __launch_bounds__(1024) void k_scan(const u64* __restrict__ hist,
                                               u64* __restrict__ rc){
  int bn = blockIdx.x;
  const u64* h = hist + (size_t)bn*NBINS;
  u64* o = rc + (size_t)bn*NBINS;
  const int PT = NBINS/1024;  // 32
  int tid = threadIdx.x;
  int lane = tid & 63, wave = tid >> 6;
  u64 loc[PT]; u64 s = 0;
  #pragma unroll
  for(int k=0;k<PT;k++){
    int q = tid*PT + k;               // reversed coord: bin = NBINS-1-q
    loc[k] = h[NBINS-1-q];
    s += loc[k];
  }
  u64 sc = s;
  #pragma unroll
  for(int off=1;off<64;off<<=1){ u64 vv = __shfl_up(sc, off, 64); if(lane>=off) sc += vv; }
  __shared__ u64 wsum[16];
  if(lane==63) wsum[wave] = sc;
  __syncthreads();
  if(tid==0){
    u64 run = 0;
    #pragma unroll
    for(int w=0;w<16;w++){ u64 tmp = wsum[w]; wsum[w] = run; run += tmp; }
  }
  __syncthreads();
  u64 excl = wsum[wave] + (sc - s);
  #pragma unroll
  for(int k=0;k<PT;k++){
    o[NBINS-1-(tid*PT+k)] = excl;
    excl += loc[k];
  }
}

// ---------------- Pass E: ranks via cursor atomics + lovasz grad -------------
__global__ void k_final(const float* __restrict__ err, const int* __restrict__ gt,
                        const u64* __restrict__ rc, u64* __restrict__ cursor,
                        const float* __restrict__ cnt, float* __restrict__ out){
  int b = blockIdx.x;
  int p = blockIdx.y*256 + threadIdx.x;
  int lane = threadIdx.x & 63, wave = threadIdx.x >> 6;
  u64 lmask_lt = ((u64)1 << lane) - 1;
  float lsum = 0.f;

  #pragma unroll
  for(int n=0;n<N_;n++){
    int bn = b*N_ + n;
    float e = err[(size_t)bn*P_ + p];
    int  mi = gt[(size_t)bn*P_ + p];
    u32 bin = (u32)min(NBINS-1, (int)(e * (NBINS/2)));
    u64* cp = cursor + (size_t)bn*NBINS;

    u64 mball = __ballot(mi != 0);
    u64 active = __ballot(1);
    u64 myold = 0;
    while(active){
      int leader = __ffsll(active) - 1;
      u32 lbin = (u32)__shfl((int)bin, leader, 64);
      u64 match = __ballot(bin == lbin) & active;
      u64 old = 0;
      if(lane == leader){
        u64 cntm = (u64)__popcll(match);
        u64 labm = (u64)__popcll(match & mball);
        old = atomicAdd(&cp[lbin], (cntm<<32) | labm);
      }
      u64 oldb = __shfl(old, leader, 64);
      if(bin == lbin){
        u64 before = match & lmask_lt;
        u64 cb = (u64)__popcll(before);
        u64 lb = (u64)__popcll(before & mball);
        myold = oldb + (cb<<32) + lb;
      }
      active &= ~match;
    }

    u64 base = rc[(size_t)bn*NBINS + bin];
    float G  = cnt[bn];
    float fi   = (float)((u32)(myold>>32) + (u32)(base>>32));           // rank i
    float cinc = (float)((u32)(myold & 0xffffffffu) + (u32)(base & 0xffffffffu))
               + (float)mi;                                              // inclusive label prefix
    float jc = 1.f - (G - cinc)/(G + fi + 1.f - cinc);
    float cpv = cinc - (float)mi;
    float jp = 1.f - (G - cpv)/(G + fi - cpv);   // i=0: cpv=0 -> jp = 0
    lsum += fmaxf(e, 0.f) * (jc - jp);
  }

  __shared__ float rs[4];
  float tot = waveReduceSum(lsum);
  if(lane==0) rs[wave] = tot;
  __syncthreads();
  if(threadIdx.x==0){
    float s2 = rs[0]+rs[1]+rs[2]+rs[3];
    atomicAdd(out, s2 * (1.0f/(float)NINST));
  }
}

extern "C" void kernel_launch(void* const* d_in, const int* in_sizes, int n_in,
                              void* d_out, int out_size, void* d_ws, size_t ws_size,
                              hipStream_t stream){
  const float* mf1 = (const float*)d_in[0];
  const float* mf2 = (const float*)d_in[1];
  const int*   gt  = (const int*)d_in[2];
  float* out = (float*)d_out;

  // ws layout
  float* sumEmb = (float*)d_ws;      // 384
  float* cnt    = sumEmb + 384;      // 24
  float* mean   = cnt + 24;          // 384
  float* sumD2  = mean + 384;        // 384
  float* var    = sumD2 + 384;       // 384
  const size_t HIST_BYTES = (size_t)NINST * NBINS * sizeof(u64);   // 6.29 MB
  u64*   hist = (u64*)((char*)d_ws + 8192);
  u64*   rc   = (u64*)((char*)hist + HIST_BYTES);
  float* err  = (float*)((char*)rc + HIST_BYTES);                   // 8.85 MB

  hipMemsetAsync(d_ws, 0, 8192, stream);
  hipMemsetAsync(hist, 0, HIST_BYTES, stream);
  hipMemsetAsync(d_out, 0, sizeof(float), stream);

  k_sums<<<dim3(NINST, P_/1024), 256, 0, stream>>>(mf1, mf2, gt, sumEmb, cnt);
  k_fin_mean<<<1, 384, 0, stream>>>(sumEmb, cnt, mean);
  k_var<<<dim3(NINST, P_/1024), 256, 0, stream>>>(mf1, mf2, gt, mean, sumD2);
  k_fin_var<<<1, 384, 0, stream>>>(sumD2, cnt, var);

  k_err<<<dim3(B_, P_/256), 256, 0, stream>>>(mf1, mf2, gt, mean, var, err, hist);
  k_scan<<<NINST, 1024, 0, stream>>>(hist, rc);
  hipMemsetAsync(hist, 0, HIST_BYTES, stream);   // reuse as cursor
  k_final<<<dim3(B_, P_/256), 256, 0, stream>>>(err, gt, rc, hist, cnt, out);
}

// Round 3
// 140.704 us; speedup vs baseline: 8.8016x; 8.8016x over previous
//
#include <hip/hip_runtime.h>
#include <cstdint>

#define B_ 2
#define E_ 16
#define H_ 160
#define W_ 288
#define N_ 12
#define T_ 2
#define HW_ (H_*W_)        // 46080
#define P_ (T_*HW_)        // 92160
#define NINST (B_*N_)      // 24
#define NBINS 4096         // err in [0,2] -> bin = min(4095, err*2048)
#define BINSCALE 2048.0f

typedef unsigned long long u64;
typedef unsigned int u32;

__device__ inline float waveReduceSum(float v){
  #pragma unroll
  for(int o=32;o>0;o>>=1) v += __shfl_down(v, o, 64);
  return v;
}

// ---- Pass A: fused masked sum + sum-of-squares + count (mean & var in one pass)
// var = (sum(m*x^2) - cnt*mu^2) / (cnt-1); identical to ref within fp32 noise.
__global__ void k_stats(const float* __restrict__ mf1, const float* __restrict__ mf2,
                        const int* __restrict__ gt,
                        float* __restrict__ sumEmb, float* __restrict__ sumSq,
                        float* __restrict__ cnt){
  int bn = blockIdx.x;               // 0..23
  int b  = bn / N_;
  int base = blockIdx.y * 1024;      // 90 chunks
  int t = base / HW_;
  int rbase = base - t*HW_;
  const float* ep = (t ? mf2 : mf1) + (size_t)b*E_*HW_;
  const int*   gp = gt + ((size_t)bn*T_ + t)*HW_;

  float s[E_], q[E_]; float c = 0.f;
  #pragma unroll
  for(int e=0;e<E_;e++){ s[e]=0.f; q[e]=0.f; }
  #pragma unroll
  for(int k=0;k<4;k++){
    int r = rbase + k*256 + threadIdx.x;
    float m = (float)gp[r];
    c += m;
    #pragma unroll
    for(int e=0;e<E_;e++){
      float x = ep[(size_t)e*HW_ + r];
      float mx = m*x;
      s[e] += mx;
      q[e] = fmaf(mx, x, q[e]);
    }
  }
  __shared__ float red[2*E_+1];
  if(threadIdx.x < 2*E_+1) red[threadIdx.x] = 0.f;
  __syncthreads();
  int lane = threadIdx.x & 63;
  #pragma unroll
  for(int e=0;e<E_;e++){
    float r1 = waveReduceSum(s[e]);
    if(lane==0) atomicAdd(&red[e], r1);
    float r2 = waveReduceSum(q[e]);
    if(lane==0) atomicAdd(&red[E_+e], r2);
  }
  { float r = waveReduceSum(c); if(lane==0) atomicAdd(&red[2*E_], r); }
  __syncthreads();
  if(threadIdx.x < E_)            atomicAdd(&sumEmb[bn*E_ + threadIdx.x], red[threadIdx.x]);
  else if(threadIdx.x < 2*E_)     atomicAdd(&sumSq [bn*E_ + threadIdx.x - E_], red[threadIdx.x]);
  else if(threadIdx.x == 2*E_)    atomicAdd(&cnt[bn], red[2*E_]);
}

__global__ void k_fin(const float* __restrict__ sumEmb, const float* __restrict__ sumSq,
                      const float* __restrict__ cnt,
                      float* __restrict__ mean, float* __restrict__ var){
  int i = threadIdx.x;  // 384
  float c  = cnt[i>>4];
  float mu = sumEmb[i] / c;
  mean[i] = mu;
  var[i]  = (sumSq[i] - c*mu*mu) / (c - 1.0f);
}

// ---- Pass B: per-instance LDS histogram of (count, labelsum, errsum) over 4096 bins.
// One block = one instance x 3072-pixel chunk. LDS atomics absorb the hot-bin
// contention; one skip-empty global merge per block.
__global__ __launch_bounds__(256) void k_err(const float* __restrict__ mf1,
                                             const float* __restrict__ mf2,
                                             const int* __restrict__ gt,
                                             const float* __restrict__ mean,
                                             const float* __restrict__ var,
                                             u64* __restrict__ hist,
                                             float* __restrict__ esum){
  __shared__ u32   hcl[NBINS];   // count<<16 | labelsum  (block-local: fits 16 bits)
  __shared__ float hes[NBINS];
  int bn = blockIdx.x;
  int b  = bn / N_;
  for(int i=threadIdx.x; i<NBINS; i+=256){ hcl[i]=0u; hes[i]=0.f; }

  float mn[E_], sv[E_];
  #pragma unroll
  for(int e=0;e<E_;e++){ mn[e]=mean[bn*E_+e]; sv[e]=var[bn*E_+e]; }

  int pbase = blockIdx.y * 3072;        // 30 chunks; 3072 | HW_ so t is uniform
  int t = pbase / HW_;
  int rbase = pbase - t*HW_;
  const float* ep = (t ? mf2 : mf1) + (size_t)b*E_*HW_;
  const int*   gp = gt + (size_t)bn*P_ + pbase;
  __syncthreads();

  #pragma unroll
  for(int it=0; it<12; ++it){
    int r = rbase + it*256 + threadIdx.x;
    float d = 0.f;
    #pragma unroll
    for(int e=0;e<E_;e++){
      float df = ep[(size_t)e*HW_ + r] - mn[e];
      d = fmaf(df*df, sv[e], d);
    }
    float logits = 2.f*__expf(-0.5f*d) - 1.f;
    int   mi = gp[it*256 + threadIdx.x];
    float ev = fmaxf(1.f - logits*(2.f*(float)mi - 1.f), 0.f);   // in [0,2]
    int bin = min(NBINS-1, (int)(ev * BINSCALE));
    atomicAdd(&hcl[bin], 0x10000u | (u32)mi);
    atomicAdd(&hes[bin], ev);
  }
  __syncthreads();

  u64*   hp = hist + (size_t)bn*NBINS;
  float* sp = esum + (size_t)bn*NBINS;
  for(int i=threadIdx.x; i<NBINS; i+=256){
    u32 v = hcl[i];
    if(v){
      atomicAdd(&hp[i], ((u64)(v>>16)<<32) | (u64)(v & 0xffffu));
      atomicAdd(&sp[i], hes[i]);
    }
  }
}

// ---- Pass C: per-instance descending scan over bins + closed-form lovasz dot.
// Within-bin grads telescope (jaccard is monotone): contribution =
// (errsum/count) * (jacc(i0+cnt-1, c0+lab) - jacc(i0-1, c0)).
__global__ __launch_bounds__(256) void k_bins(const u64* __restrict__ hist,
                                              const float* __restrict__ esum,
                                              const float* __restrict__ cnt,
                                              float* __restrict__ out){
  const int PT = NBINS/256;   // 16 bins per thread (reversed order)
  int bn = blockIdx.x;
  const u64*   h  = hist + (size_t)bn*NBINS;
  const float* es = esum + (size_t)bn*NBINS;
  int tid = threadIdx.x, lane = tid & 63, wave = tid >> 6;

  u64 loc[PT]; u64 s = 0;
  #pragma unroll
  for(int k=0;k<PT;k++){
    loc[k] = h[NBINS-1 - (tid*PT + k)];
    s += loc[k];
  }
  u64 sc = s;
  #pragma unroll
  for(int off=1;off<64;off<<=1){ u64 v = __shfl_up(sc, off, 64); if(lane>=off) sc += v; }
  __shared__ u64 wsum[4], wbase[4];
  if(lane==63) wsum[wave] = sc;
  __syncthreads();
  if(tid==0){
    u64 run = 0;
    #pragma unroll
    for(int w=0;w<4;w++){ wbase[w] = run; run += wsum[w]; }
  }
  __syncthreads();
  u64 excl = wbase[wave] + (sc - s);

  float G = cnt[bn];
  float lsum = 0.f;
  #pragma unroll
  for(int k=0;k<PT;k++){
    u64 lv = loc[k];
    u32 cb = (u32)(lv>>32), lb = (u32)(lv & 0xffffffffu);
    if(cb){
      float i0 = (float)(u32)(excl>>32);
      float c0 = (float)(u32)(excl & 0xffffffffu);
      float c1 = c0 + (float)lb;
      float jend   = 1.f - (G - c1)/(G + i0 + (float)cb - c1);
      float jstart = 1.f - (G - c0)/(G + i0 - c0);   // i0=0,c0=0 -> 0
      lsum += (es[NBINS-1 - (tid*PT + k)] / (float)cb) * (jend - jstart);
    }
    excl += lv;
  }

  __shared__ float rs[4];
  float tot = waveReduceSum(lsum);
  if(lane==0) rs[wave] = tot;
  __syncthreads();
  if(tid==0) atomicAdd(out, (rs[0]+rs[1]+rs[2]+rs[3]) * (1.0f/(float)NINST));
}

extern "C" void kernel_launch(void* const* d_in, const int* in_sizes, int n_in,
                              void* d_out, int out_size, void* d_ws, size_t ws_size,
                              hipStream_t stream){
  const float* mf1 = (const float*)d_in[0];
  const float* mf2 = (const float*)d_in[1];
  const int*   gt  = (const int*)d_in[2];
  float* out = (float*)d_out;

  // ws layout (contiguous so one memset covers everything)
  float* sumEmb = (float*)d_ws;        // 384
  float* cnt    = sumEmb + 384;        // 24
  float* mean   = cnt + 24;            // 384
  float* var    = mean + 384;          // 384
  float* sumSq  = var + 384;           // 384
  u64*   hist   = (u64*)((char*)d_ws + 8192);                 // 24*4096*8 = 768 KB
  float* esum   = (float*)((char*)hist + (size_t)NINST*NBINS*8); // 384 KB
  size_t zbytes = 8192 + (size_t)NINST*NBINS*8 + (size_t)NINST*NBINS*4;

  hipMemsetAsync(d_ws, 0, zbytes, stream);
  hipMemsetAsync(d_out, 0, sizeof(float), stream);

  k_stats<<<dim3(NINST, P_/1024), 256, 0, stream>>>(mf1, mf2, gt, sumEmb, sumSq, cnt);
  k_fin<<<1, 384, 0, stream>>>(sumEmb, sumSq, cnt, mean, var);
  k_err<<<dim3(NINST, P_/3072), 256, 0, stream>>>(mf1, mf2, gt, mean, var, hist, esum);
  k_bins<<<NINST, 256, 0, stream>>>(hist, esum, cnt, out);
}